// Round 13
// baseline (405.974 us; speedup 1.0000x reference)
//
#include <hip/hip_runtime.h>

typedef unsigned short u16;
typedef unsigned int   u32;
typedef __attribute__((ext_vector_type(8)))  __bf16 bf16x8;
typedef __attribute__((ext_vector_type(4)))  float  f32x4;
typedef __attribute__((ext_vector_type(16))) float  f32x16;
typedef __attribute__((ext_vector_type(4)))  unsigned short u16x4;

#define DEV static __device__ __forceinline__

// 0.125 * log2(e): folded into Wq/bq at weight-cast time; scores are in exp2 units
#define SC 0.1803368801111243f

DEV u16 cvt_bf16(float f){
  u32 u = __builtin_bit_cast(u32, f);
  u32 r = (u + 0x7FFFu + ((u >> 16) & 1u)) >> 16;   // round-to-nearest-even
  return (u16)r;
}
DEV float bf2f(u16 v){ return __builtin_bit_cast(float, (u32)v << 16); }

typedef __attribute__((address_space(1))) void* as1p;
typedef __attribute__((address_space(3))) void* as3p;

DEV void gld16(void* lds, const void* g){
  __builtin_amdgcn_global_load_lds((as1p)g, (as3p)lds, 16, 0, 0);
}

DEV f32x4 mfma16(bf16x8 a, bf16x8 b, f32x4 c){
  return __builtin_amdgcn_mfma_f32_16x16x32_bf16(a, b, c, 0, 0, 0);
}
DEV f32x16 mfma32(bf16x8 a, bf16x8 b, f32x16 c){
  return __builtin_amdgcn_mfma_f32_32x32x16_bf16(a, b, c, 0, 0, 0);
}

DEV bf16x8 ld8(const u16* p){ return *(const bf16x8*)p; }

DEV float vexp2(float x){            // native 2^x
  float y; asm("v_exp_f32 %0, %1" : "=v"(y) : "v"(x)); return y;
}

DEV u32 cvtpk(float lo, float hi){
  u32 r; asm("v_cvt_pk_bf16_f32 %0, %1, %2" : "=v"(r) : "v"(lo), "v"(hi)); return r;
}
DEV void perm32swap(u32 &a, u32 &b){
  asm("v_permlane32_swap_b32 %0, %1" : "+v"(a), "+v"(b));
}
DEV bf16x8 frag4(u32 w0,u32 w1,u32 w2,u32 w3){
  union{ u32 w[4]; bf16x8 f; } u; u.w[0]=w0; u.w[1]=w1; u.w[2]=w2; u.w[3]=w3; return u.f;
}

// XOR swizzles (T2/T21)
DEV int swz64(int row, int blk){ return row*64 + ((blk ^ (row & 7)) << 3); } // 128B rows
DEV int swz32(int row, int blk){ return row*32 + ((blk ^ (row & 3)) << 3); } // 64B rows

// ---------------- fused cast f32 -> bf16 (x and enc in one launch) ----------------
__global__ __launch_bounds__(256) void castk2(const float* __restrict__ in0,
                                              u16* __restrict__ out0,
                                              const float* __restrict__ in1,
                                              u16* __restrict__ out1){
  const float* in = blockIdx.y ? in1 : in0;
  u16*        out = blockIdx.y ? out1 : out0;
  int i = blockIdx.x*256 + threadIdx.x;
  f32x4 v = *(const f32x4*)(in + (size_t)i*4);
  u16x4 o;
  #pragma unroll
  for(int j=0;j<4;j++) o[j] = cvt_bf16(v[j]);
  *(u16x4*)(out + (size_t)i*4) = o;
}

// -------- fused small pre-pass: bias concats (Q-bias pre-scaled) + mask bias --------
__global__ __launch_bounds__(256) void smallfuse(
    const float* __restrict__ sabq, const float* __restrict__ sabk,
    const float* __restrict__ sabv, const float* __restrict__ cabk,
    const float* __restrict__ cabv, const float* __restrict__ cabq,
    const int* __restrict__ pm,
    float* __restrict__ bqkv, float* __restrict__ bkvc,
    float* __restrict__ biasg, float* __restrict__ bqc){
  int i = blockIdx.x*256 + threadIdx.x;   // 0..8191
  if(i < 1024)       bqkv[i] = sabq[i]*SC;
  else if(i < 2048)  bqkv[i] = sabk[i-1024];
  else if(i < 3072)  bqkv[i] = sabv[i-2048];
  else if(i < 4096)  bkvc[i-3072] = cabk[i-3072];
  else if(i < 5120)  bkvc[i-3072] = cabv[i-4096];
  else if(i < 7168)  biasg[i-5120] = pm[i-5120] ? 0.f : -1e9f;
  else if(i < 8192)  bqc[i-7168] = cabq[i-7168]*SC;
}

// ---------------- weight transpose-cast: f32[K,N] -> bf16[N,K] (optional scale) -----
DEV void wcast_body(const float* __restrict__ W, u16* __restrict__ Wt,
                    int K, int N, int bx, int by, int tid, float scale){
  __shared__ u16 tile[64][66];
  const int k0 = bx*64, n0 = by*64;
  const int lr = tid >> 4, c4 = (tid & 15)*4;
  #pragma unroll
  for(int p=0;p<4;p++){
    const int r = lr + p*16;
    f32x4 v = *(const f32x4*)&W[(size_t)(k0+r)*N + n0 + c4];
    #pragma unroll
    for(int j=0;j<4;j++) tile[r][c4+j] = cvt_bf16(v[j]*scale);
  }
  __syncthreads();
  #pragma unroll
  for(int p=0;p<4;p++){
    const int n = lr + p*16;
    u16x4 u;
    #pragma unroll
    for(int j=0;j<4;j++) u[j] = tile[c4+j][n];
    *(u16x4*)&Wt[(size_t)(n0+n)*K + k0 + c4] = u;
  }
}

__global__ __launch_bounds__(256) void wcast_t(const float* __restrict__ W,
                                               u16* __restrict__ Wt, int K, int N){
  wcast_body(W, Wt, K, N, blockIdx.x, blockIdx.y, threadIdx.x, 1.f);
}

// eight 1024x1024 weights in one launch; slots 0 (Wq) and 4 (cWq) pre-scaled by SC
__global__ __launch_bounds__(256) void wcast8(
    const float* s0, const float* s1, const float* s2, const float* s3,
    const float* s4, const float* s5, const float* s6, const float* s7,
    u16* d0, u16* d1, u16* d2, u16* d3, u16* d4, u16* d5, u16* d6, u16* d7){
  const float* W; u16* Wt;
  switch(blockIdx.z){
    case 0: W=s0; Wt=d0; break;  case 1: W=s1; Wt=d1; break;
    case 2: W=s2; Wt=d2; break;  case 3: W=s3; Wt=d3; break;
    case 4: W=s4; Wt=d4; break;  case 5: W=s5; Wt=d5; break;
    case 6: W=s6; Wt=d6; break;  default: W=s7; Wt=d7; break;
  }
  const float scale = (blockIdx.z==0 || blockIdx.z==4) ? SC : 1.f;
  wcast_body(W, Wt, 1024, 1024, blockIdx.x, blockIdx.y, threadIdx.x, scale);
}

// ---------------- V transpose per (b,h): [B*L, ld] -> [B,H,64,L] ----------------
__global__ __launch_bounds__(256) void vtrans(const u16* __restrict__ V,
                                              u16* __restrict__ Vt, int L, int ld){
  __shared__ u16 tile[64][66];
  const int t0 = blockIdx.x*64;
  const int h = blockIdx.y, b = blockIdx.z;
  const int lr = threadIdx.x >> 4, c4 = (threadIdx.x & 15)*4;
  #pragma unroll
  for(int p=0;p<4;p++){
    const int r = lr + p*16;
    u16x4 v = *(const u16x4*)&V[(size_t)(b*L + t0 + r)*ld + h*64 + c4];
    #pragma unroll
    for(int j=0;j<4;j++) tile[r][c4+j] = v[j];
  }
  __syncthreads();
  #pragma unroll
  for(int p=0;p<4;p++){
    const int d = lr + p*16;
    u16x4 u;
    #pragma unroll
    for(int j=0;j<4;j++) u[j] = tile[c4+j][d];
    *(u16x4*)&Vt[((size_t)((b*16 + h)*64 + d))*L + t0 + c4] = u;
  }
}

// ---------------- GEMM: C[M,N] = A[M,K](bf16) * Bt[N,K](bf16)^T + bias ----------------
// T3/T4 counted-vmcnt pipeline: TRIPLE-buffered LDS, prefetch distance 2,
// per-tile s_waitcnt vmcnt(LOADS) + raw s_barrier (vmcnt(0) only on the last tile).
// Safety: each wave value-consumes its ds_reads (lgkm-forced) before its barrier,
// so restaging a buffer (issued only after that barrier) is WAR-safe; staged data
// is covered by each wave waiting its own vmcnt before the barrier.
// GEMM has the VGPR headroom attn lacked (R11 lesson): VGPR ~40 -> pipeline is free.
template<int OMODE, int BN, int SPLITK>
__global__ __launch_bounds__(256, BN==128 ? 3 : 4) void gemm_bt(
    const u16* __restrict__ A, const u16* __restrict__ Bt,
    const float* __restrict__ bias, void* __restrict__ Cout0, void* __restrict__ Cout1,
    int N, int K)
{
  __shared__ __align__(16) u16 As[3][128*32];
  __shared__ __align__(16) u16 Bs[3][BN*32];
  constexpr int NJ = BN/32;
  constexpr int LOADS = (BN==128) ? 4 : 3;
  const int tid = threadIdx.x, wave = tid>>6, lane = tid&63;
  const int fr = lane&15, fg = lane>>4;
  const int bm = blockIdx.x*128, bn = blockIdx.y*BN;
  const int part = (SPLITK>1) ? blockIdx.z : 0;
  const int Kp = K / SPLITK;
  const int kbase = part * Kp;
  const int wm = (wave>>1)*64, wn = (wave&1)*(BN/2);
  const f32x4 z4 = {0.f,0.f,0.f,0.f};
  f32x4 acc[4][NJ];
  #pragma unroll
  for(int i=0;i<4;i++)
    #pragma unroll
    for(int j=0;j<NJ;j++) acc[i][j] = z4;

  const int srA = wave*32 + (lane>>2);
  const int cl_l = (lane&3)*8;
  const int cl_g = ((lane&3) ^ ((lane>>2)&3))*8;
  const int srB = (BN==128) ? srA : (wave*16 + (lane>>2));
  const u16* gA = A  + (size_t)(bm + srA)*K + kbase + cl_g;
  const u16* gB = Bt + (size_t)(bn + srB)*K + kbase + cl_g;

  auto stage = [&](int p, int ko){
    u16* lA = &As[p][srA*32 + cl_l];
    u16* lB = &Bs[p][srB*32 + cl_l];
    gld16(lA,     gA + ko);
    gld16(lA+512, gA + ko + (size_t)16*K);
    gld16(lB,     gB + ko);
    if(BN==128) gld16(lB+512, gB + ko + (size_t)16*K);
  };

  const int nk = Kp >> 5;
  stage(0, 0);
  if(nk > 1) stage(1, 32);
  int cur = 0;
  for(int kt=0; kt<nk; ++kt){
    // counted wait: tile kt's stage complete; tile kt+1's LOADS may stay in flight
    if(kt+1 < nk){
      if constexpr (LOADS==4) asm volatile("s_waitcnt vmcnt(4)" ::: "memory");
      else                    asm volatile("s_waitcnt vmcnt(3)" ::: "memory");
    } else {
      asm volatile("s_waitcnt vmcnt(0)" ::: "memory");
    }
    __builtin_amdgcn_s_barrier();
    asm volatile("" ::: "memory");
    if(kt+2 < nk){
      int nb = cur+2; if(nb>=3) nb-=3;
      stage(nb, (kt+2)*32);
    }
    bf16x8 af[4], bfv[NJ];
    #pragma unroll
    for(int i=0;i<4;i++) af[i] = ld8(&As[cur][swz32(wm + i*16 + fr, fg)]);
    #pragma unroll
    for(int j=0;j<NJ;j++) bfv[j] = ld8(&Bs[cur][swz32(wn + j*16 + fr, fg)]);
    __builtin_amdgcn_s_setprio(1);
    #pragma unroll
    for(int i=0;i<4;i++)
      #pragma unroll
      for(int j=0;j<NJ;j++)
        acc[i][j] = mfma16(af[i], bfv[j], acc[i][j]);
    __builtin_amdgcn_s_setprio(0);
    cur = (cur==2) ? 0 : cur+1;
  }

  void* Cout = (part==0) ? Cout0 : Cout1;
  const int r0 = bm + wm + fg*4;
  const int c0 = bn + wn + fr;
  #pragma unroll
  for(int j=0;j<NJ;j++){
    const int col = c0 + j*16;
    const float bv = (part==0) ? bias[col] : 0.f;
    #pragma unroll
    for(int i=0;i<4;i++){
      #pragma unroll
      for(int r=0;r<4;r++){
        const float v = acc[i][j][r] + bv;
        const size_t idx = (size_t)(r0 + i*16 + r)*N + col;
        if(OMODE==0)      ((float*)Cout)[idx] = v;
        else if(OMODE==1) ((u16*)Cout)[idx]   = cvt_bf16(v);
        else              ((u16*)Cout)[idx]   = cvt_bf16(fmaxf(v, 0.f));
      }
    }
  }
}

// ---------------- flash attention, KV-split xNPART, FIXED-SHIFT softmax ------------
// Q pre-scaled by SC so scores are in exp2 units; P = 2^s directly (no online max:
// exact vs softmax modulo over/underflow, >100 exp2-units of margin).
// R9's proven schedule: double-buffered LDS (32 KiB), one __syncthreads per tile.
// (Counted-vmcnt here raised VGPR 60->84 -> occupancy loss, R11: keep syncthreads.)
// Partials stored BF16. (256,4): VGPR ~60 fits -- (256,5) forced 48 and SPILLED (R7).
template<bool CAUSAL, int NPART>
__global__ __launch_bounds__(256,4) void attn3(
    const u16* __restrict__ Qg, int ldq, const u16* __restrict__ Kg, int ldk,
    const u16* __restrict__ Vt, const float* __restrict__ biasg,
    u16* __restrict__ O0, u16* __restrict__ O1,
    u16* __restrict__ O2, u16* __restrict__ O3,
    float* __restrict__ Ll, int Lk)
{
  __shared__ __align__(16) u16 Ks[2][64*64];
  __shared__ __align__(16) u16 Vs[2][64*64];
  constexpr int P2 = NPART*16;
  const int tid = threadIdx.x, wave = tid>>6, lane = tid&63;
  const int l31 = lane&31, hi = lane>>5;
  const int bid = blockIdx.x;
  const int g    = (bid&7)*4 + ((bid>>3)/P2);   // (b,h) group 0..31, XCD-resident
  const int rp   = (bid>>3)%P2;
  const int part = rp&(NPART-1), qb = rp/NPART;
  const int h = g&15, b = g>>4;
  // causal: pair-swizzle so heavy and light q-blocks interleave
  const int qi = CAUSAL ? ((qb&1) ? (15-(qb>>1)) : (qb>>1)) : qb;
  const int q0 = qi*128;
  const int qw = q0 + wave*32;
  const int qrow = qw + l31;                 // this lane's q-row (softmax owner)

  bf16x8 qf[4];
  {
    const u16* Qp = Qg + (size_t)(b*2048 + qrow)*ldq + h*64;
    #pragma unroll
    for(int c=0;c<4;c++) qf[c] = ld8(Qp + c*16 + hi*8);
  }

  f32x16 o0, o1;
  #pragma unroll
  for(int r=0;r<16;r++){ o0[r]=0.f; o1[r]=0.f; }
  float lsum = 0.f;

  const int srow = wave*16 + (lane>>3);
  const int cl_l = (lane&7)*8;
  const int cl_g = ((lane&7) ^ ((lane>>3)&7))*8;
  const u16* Kp = Kg + (size_t)(b*2048 + srow)*ldk + h*64 + cl_g;
  const u16* Vp = Vt + ((size_t)((b*16 + h)*64 + srow))*Lk + cl_g;

  auto stage = [&](int p, int kv0){
    u16* lK = &Ks[p][srow*64 + cl_l];
    u16* lV = &Vs[p][srow*64 + cl_l];
    gld16(lK,     Kp + (size_t)kv0*ldk);
    gld16(lK+512, Kp + (size_t)(kv0+8)*ldk);
    gld16(lV,     Vp + kv0);
    gld16(lV+512, Vp + kv0 + 8*(size_t)Lk);
  };

  // tile range for this part (variable split; empty parts write O=0, l=0)
  const int T  = CAUSAL ? (2*qi+2) : (Lk>>6);
  const int t0 = part*T/NPART, t1 = (part+1)*T/NPART;

  stage(0, t0*64);
  __syncthreads();
  for(int kt=t0; kt<t1; ++kt){
    const int cur = (kt-t0)&1;
    const int kv0 = kt*64;
    if(kt+1 < t1) stage(cur^1, (kt+1)*64);

    if(!CAUSAL || kv0 <= qw+31){   // wave-uniform: skip fully-masked tiles
      // S^T = K Q^T : lane holds col q=l31; rows k=(r&3)+8(r>>2)+4hi (+32 for s1)
      f32x16 s0, s1;
      #pragma unroll
      for(int r=0;r<16;r++){ s0[r]=0.f; s1[r]=0.f; }
      __builtin_amdgcn_s_setprio(1);
      #pragma unroll
      for(int c=0;c<4;c++){
        bf16x8 k0 = ld8(&Ks[cur][swz64(l31,      2*c+hi)]);
        bf16x8 k1 = ld8(&Ks[cur][swz64(32 + l31, 2*c+hi)]);
        s0 = mfma32(k0, qf[c], s0);
        s1 = mfma32(k1, qf[c], s1);
      }
      __builtin_amdgcn_s_setprio(0);

      float p[32];
      #pragma unroll
      for(int r=0;r<16;r++){ p[r]=s0[r]; p[16+r]=s1[r]; }

      if(CAUSAL){
        if(kv0 + 63 > qw){         // diagonal tile only
          #pragma unroll
          for(int n=0;n<2;n++)
            #pragma unroll
            for(int r=0;r<16;r++){
              const int kc = kv0 + 32*n + (r&3) + 8*(r>>2) + 4*hi;
              if(kc > qrow) p[16*n+r] = -1e9f;
            }
        }
      } else {
        #pragma unroll
        for(int n=0;n<2;n++)
          #pragma unroll
          for(int cq=0;cq<4;cq++){
            f32x4 bv = *(const f32x4*)&biasg[kv0 + 32*n + 8*cq + 4*hi];
            #pragma unroll
            for(int i=0;i<4;i++) p[16*n+4*cq+i] += bv[i];
          }
      }

      // fixed-shift softmax: P = 2^s, no max reduction, no rescale, no branches
      float rs0=0.f, rs1=0.f, rs2=0.f, rs3=0.f;
      #pragma unroll
      for(int r=0;r<8;r++){
        p[r]    = vexp2(p[r]);    rs0 += p[r];
        p[8+r]  = vexp2(p[8+r]);  rs1 += p[8+r];
        p[16+r] = vexp2(p[16+r]); rs2 += p[16+r];
        p[24+r] = vexp2(p[24+r]); rs3 += p[24+r];
      }
      float rs = (rs0+rs1) + (rs2+rs3);
      rs += __shfl_xor(rs, 32);
      lsum += rs;

      // P -> bf16 A-frags fully in-register (cvt_pk + permlane32_swap)
      u32 pw[16];
      #pragma unroll
      for(int n=0;n<2;n++)
        #pragma unroll
        for(int cp=0;cp<2;cp++){
          const int base = 16*n + 8*cp, cc = 2*n + cp;
          u32 a1 = cvtpk(p[base+0], p[base+1]);
          u32 a2 = cvtpk(p[base+2], p[base+3]);
          u32 b1 = cvtpk(p[base+4], p[base+5]);
          u32 b2 = cvtpk(p[base+6], p[base+7]);
          perm32swap(a1, b1);
          perm32swap(a2, b2);
          pw[4*cc+0]=a1; pw[4*cc+1]=a2; pw[4*cc+2]=b1; pw[4*cc+3]=b2;
        }

      // O += P V
      __builtin_amdgcn_s_setprio(1);
      #pragma unroll
      for(int cc=0;cc<4;cc++){
        bf16x8 pf = frag4(pw[4*cc], pw[4*cc+1], pw[4*cc+2], pw[4*cc+3]);
        bf16x8 v0 = ld8(&Vs[cur][swz64(l31,      2*cc+hi)]);
        bf16x8 v1 = ld8(&Vs[cur][swz64(32 + l31, 2*cc+hi)]);
        o0 = mfma32(pf, v0, o0);
        o1 = mfma32(pf, v1, o1);
      }
      __builtin_amdgcn_s_setprio(0);
    }
    __syncthreads();   // drains prefetch (overlapped) + protects restage
  }

  // epilogue: unnormalized O partial (bf16) + per-row l, [part][h][row] layout
  u16* Obase = (part==0) ? O0 : (part==1) ? O1 : (part==2) ? O2 : O3;
  u16* Op = Obase + (size_t)(b*2048 + qw)*1024 + h*64;
  #pragma unroll
  for(int r=0;r<16;r++){
    const int qidx = (r&3) + 8*(r>>2) + 4*hi;
    Op[(size_t)qidx*1024 + l31]      = cvt_bf16(o0[r]);
    Op[(size_t)qidx*1024 + 32 + l31] = cvt_bf16(o1[r]);
  }
  if(hi==0){
    const int mi = part*65536 + h*4096 + (b*2048 + qw + l31);
    Ll[mi] = lsum;
  }
}

// ---------------- attention partial combine over NP parts (fixed-shift: sum/sum) ----
template<int NP>
__global__ __launch_bounds__(256) void att_combine(
    const u16* __restrict__ O0, const u16* __restrict__ O1,
    const u16* __restrict__ O2, const u16* __restrict__ O3,
    const float* __restrict__ Ll, u16* __restrict__ Ob)
{
  const int row = blockIdx.x, tid = threadIdx.x;
  const int h = tid>>4;
  const int mi = h*4096 + row;
  float denom = 0.f;
  #pragma unroll
  for(int p=0;p<NP;p++) denom += Ll[p*65536 + mi];
  const float inv = 1.f/denom;
  const size_t base = (size_t)row*1024 + tid*4;
  f32x4 acc = {0.f,0.f,0.f,0.f};
  #pragma unroll
  for(int p=0;p<NP;p++){
    const u16* Op = (p==0) ? O0 : (p==1) ? O1 : (p==2) ? O2 : O3;
    u16x4 a = *(const u16x4*)(Op + base);
    #pragma unroll
    for(int j=0;j<4;j++) acc[j] += bf2f(a[j]);
  }
  u16x4 o;
  #pragma unroll
  for(int j=0;j<4;j++) o[j] = cvt_bf16(acc[j]*inv);
  *(u16x4*)(Ob + base) = o;
}

// ------ fused add + layernorm, 3-input (f32 residual + two BF16 GEMM partials) ------
__global__ __launch_bounds__(256) void add_ln3(const float* __restrict__ X,
                        const u16* __restrict__ D1, const u16* __restrict__ D2,
                        const float* __restrict__ gam, const float* __restrict__ bet,
                        float* __restrict__ outf, u16* __restrict__ outb){
  __shared__ float red[8];
  const int tid = threadIdx.x, wave = tid>>6, lane = tid&63;
  const size_t base = ((size_t)blockIdx.x << 10) + tid*4;
  f32x4 xv = *(const f32x4*)(X + base);
  u16x4 d1 = *(const u16x4*)(D1 + base);
  u16x4 d2 = *(const u16x4*)(D2 + base);
  f32x4 v;
  #pragma unroll
  for(int j=0;j<4;j++) v[j] = xv[j] + bf2f(d1[j]) + bf2f(d2[j]);
  float s = v[0]+v[1]+v[2]+v[3];
  float q = v[0]*v[0]+v[1]*v[1]+v[2]*v[2]+v[3]*v[3];
  #pragma unroll
  for(int off=1;off<64;off<<=1){ s += __shfl_xor(s,off); q += __shfl_xor(q,off); }
  if(lane==0){ red[wave]=s; red[4+wave]=q; }
  __syncthreads();
  s = red[0]+red[1]+red[2]+red[3];
  q = red[4]+red[5]+red[6]+red[7];
  const float mean = s*(1.f/1024.f);
  const float var  = q*(1.f/1024.f) - mean*mean;
  const float rr = rsqrtf(var + 1e-5f);
  const int c = tid*4;
  f32x4 y;
  #pragma unroll
  for(int j=0;j<4;j++) y[j] = (v[j]-mean)*rr*gam[c+j] + bet[c+j];
  *(f32x4*)(outf + base) = y;
  if(outb){
    u16x4 ob;
    #pragma unroll
    for(int j=0;j<4;j++) ob[j] = cvt_bf16(y[j]);
    *(u16x4*)(outb + base) = ob;
  }
}

// ---------------- host orchestration ----------------
extern "C" void kernel_launch(void* const* d_in, const int* in_sizes, int n_in,
                              void* d_out, int out_size, void* d_ws, size_t ws_size,
                              hipStream_t stream)
{
  (void)in_sizes; (void)n_in; (void)out_size; (void)ws_size;
  const float* x    = (const float*)d_in[0];
  const float* enc  = (const float*)d_in[1];
  const int*   pmask= (const int*)d_in[3];
  const float* saWq = (const float*)d_in[4];  const float* sabq = (const float*)d_in[5];
  const float* saWk = (const float*)d_in[6];  const float* sabk = (const float*)d_in[7];
  const float* saWv = (const float*)d_in[8];  const float* sabv = (const float*)d_in[9];
  const float* saWo = (const float*)d_in[10]; const float* sabo = (const float*)d_in[11];
  const float* caWq = (const float*)d_in[12]; const float* cabq = (const float*)d_in[13];
  const float* caWk = (const float*)d_in[14]; const float* cabk = (const float*)d_in[15];
  const float* caWv = (const float*)d_in[16]; const float* cabv = (const float*)d_in[17];
  const float* caWo = (const float*)d_in[18]; const float* cabo = (const float*)d_in[19];
  const float* fW1  = (const float*)d_in[20]; const float* fb1  = (const float*)d_in[21];
  const float* fW2  = (const float*)d_in[22]; const float* fb2  = (const float*)d_in[23];
  const float* l1g  = (const float*)d_in[24]; const float* l1b  = (const float*)d_in[25];
  const float* l2g  = (const float*)d_in[26]; const float* l2b  = (const float*)d_in[27];
  const float* l3g  = (const float*)d_in[28]; const float* l3b  = (const float*)d_in[29];

  // workspace layout (~176 MB)
  char* wsp = (char*)d_ws;
  size_t off = 0;
  auto take = [&](size_t bytes)->void*{ void* p = wsp + off; off += (bytes + 255) & ~(size_t)255; return p; };
  u16* slotA  = (u16*)take(8388608);    // Xbf -> Qcb -> an2b
  u16* Encb   = (u16*)take(8388608);
  u16* WqkvT  = (u16*)take(6291456);    // [3072][1024]
  u16* cWqT   = (u16*)take(2097152);
  u16* cWkvT  = (u16*)take(4194304);    // [2048][1024]
  u16* WoT    = (u16*)take(2097152);
  u16* cWoT   = (u16*)take(2097152);
  u16* W1T    = (u16*)take(8388608);
  u16* W2T    = (u16*)take(8388608);
  float* bqkv = (float*)take(16384);    // [3072]
  float* bkvc = (float*)take(16384);    // [2048]
  float* biasg= (float*)take(16384);    // padding-mask additive bias [2048]
  float* bqc  = (float*)take(16384);    // scaled cross Q bias [1024]
  u16* slotB  = (u16*)take(25165824);   // QKVb [4096][3072] -> KVc [4096][2048]
  u16* Vtb    = (u16*)take(8388608);
  u16* Ob     = (u16*)take(8388608);
  u16* an1b   = (u16*)take(8388608);    // bf16 addnorm1; head doubles as attn l scratch
  float* projf= (float*)take(16777216); // bf16 partial pair (2x8MB) per phase
  float* an1f = (float*)take(16777216); // addnorm1 f32; self attn partials; FF2 part 1
  float* an2f = (float*)take(16777216); // addnorm2 f32; Wo partial 1
  char* ffhb  = (char*)take(33554432);  // FF hidden; cross attn partials; cWo part 1
  u16* Xbf = slotA;  u16* Qcb = slotA;  u16* an2b = slotA;
  u16* QKVb = slotB; u16* KVc = slotB;
  u16* ffh   = (u16*)ffhb;
  // Self-attn bf16 partials (8 MB each): parts 0,1 in projf; parts 2,3 in an1f.
  u16* S0 = (u16*)projf;  u16* S1 = S0 + 4194304;
  u16* S2 = (u16*)an1f;   u16* S3 = S2 + 4194304;
  // Cross-attn bf16 partials: parts 0,1 in ffhb (an1f live during cross).
  u16* C0 = (u16*)ffhb;   u16* C1 = C0 + 4194304;
  // Split-K GEMM bf16 partial pairs (8 MB each):
  u16* P0 = (u16*)projf;              // part 0 (all three split GEMMs)
  u16* PWo = (u16*)an2f;              // Wo  part 1 (an2f dead pre-ln1)
  u16* PcWo= (u16*)ffhb;              // cWo part 1 (ffhb dead post-combine)
  u16* PFF = (u16*)an1f;              // FF2 part 1 (an1f dead post-ln2)
  float* Llb = (float*)an1b;            // [4][65536] = 1 MB (an1b dead during attn)

  // pre-pass (5 dispatches)
  castk2<<<dim3(4096,2),256,0,stream>>>(x, Xbf, enc, Encb);
  wcast8<<<dim3(16,16,8),256,0,stream>>>(
      saWq, saWk, saWv, saWo, caWq, caWk, caWv, caWo,
      WqkvT, WqkvT + 1024*1024, WqkvT + 2*1024*1024, WoT,
      cWqT, cWkvT, cWkvT + 1024*1024, cWoT);
  wcast_t<<<dim3(16,64),256,0,stream>>>(fW1, W1T, 1024, 4096);
  wcast_t<<<dim3(64,16),256,0,stream>>>(fW2, W2T, 4096, 1024);
  smallfuse<<<32,256,0,stream>>>(sabq, sabk, sabv, cabk, cabv, cabq, pmask,
                                 bqkv, bkvc, biasg, bqc);

  // self-attention (causal KV-split x4: critical path 8 tiles)
  gemm_bt<1,128,1><<<dim3(32,24),256,0,stream>>>(Xbf, WqkvT, bqkv, QKVb, nullptr, 3072, 1024);
  vtrans<<<dim3(32,16,2),256,0,stream>>>(QKVb + 2048, Vtb, 2048, 3072);
  attn3<true,4><<<2048,256,0,stream>>>(QKVb, 3072, QKVb + 1024, 3072, Vtb, nullptr,
                                       S0, S1, S2, S3, Llb, 2048);
  att_combine<4><<<4096,256,0,stream>>>(S0, S1, S2, S3, Llb, Ob);
  gemm_bt<1,128,2><<<dim3(32,8,2),256,0,stream>>>(Ob, WoT, sabo, P0, PWo, 1024, 1024);
  add_ln3<<<4096,256,0,stream>>>(x, P0, PWo, l1g, l1b, an1f, an1b);

  // cross-attention (KV-split x2; an1f LIVE -> partials in ffhb)
  gemm_bt<1,64,1><<<dim3(32,16),256,0,stream>>>(an1b, cWqT, bqc, Qcb, nullptr, 1024, 1024);
  gemm_bt<1,128,1><<<dim3(32,16),256,0,stream>>>(Encb, cWkvT, bkvc, KVc, nullptr, 2048, 1024);
  vtrans<<<dim3(32,16,2),256,0,stream>>>(KVc + 1024, Vtb, 2048, 2048);
  attn3<false,2><<<1024,256,0,stream>>>(Qcb, 1024, KVc, 2048, Vtb, biasg,
                                        C0, C1, nullptr, nullptr, Llb, 2048);
  att_combine<2><<<4096,256,0,stream>>>(C0, C1, nullptr, nullptr, Llb, Ob);
  gemm_bt<1,128,2><<<dim3(32,8,2),256,0,stream>>>(Ob, cWoT, cabo, P0, PcWo, 1024, 1024);
  add_ln3<<<4096,256,0,stream>>>(an1f, P0, PcWo, l2g, l2b, an2f, an2b);

  // feed-forward (FF2 split-K: bf16 partials in P0 + PFF, summed by add_ln3)
  gemm_bt<2,128,1><<<dim3(32,32),256,0,stream>>>(an2b, W1T, fb1, ffh, nullptr, 4096, 1024);
  gemm_bt<1,128,2><<<dim3(32,8,2),256,0,stream>>>(ffh, W2T, fb2, P0, PFF, 1024, 4096);
  add_ln3<<<4096,256,0,stream>>>(an2f, P0, PFF, l3g, l3b, (float*)d_out, nullptr);
}

// Round 14
// 392.299 us; speedup vs baseline: 1.0349x; 1.0349x over previous
//
#include <hip/hip_runtime.h>

typedef unsigned short u16;
typedef unsigned int   u32;
typedef __attribute__((ext_vector_type(8)))  __bf16 bf16x8;
typedef __attribute__((ext_vector_type(4)))  float  f32x4;
typedef __attribute__((ext_vector_type(16))) float  f32x16;
typedef __attribute__((ext_vector_type(4)))  unsigned short u16x4;

#define DEV static __device__ __forceinline__

// 0.125 * log2(e): folded into Wq/bq at weight-cast time; scores are in exp2 units
#define SC 0.1803368801111243f

DEV u16 cvt_bf16(float f){
  u32 u = __builtin_bit_cast(u32, f);
  u32 r = (u + 0x7FFFu + ((u >> 16) & 1u)) >> 16;   // round-to-nearest-even
  return (u16)r;
}
DEV float bf2f(u16 v){ return __builtin_bit_cast(float, (u32)v << 16); }

typedef __attribute__((address_space(1))) void* as1p;
typedef __attribute__((address_space(3))) void* as3p;

DEV void gld16(void* lds, const void* g){
  __builtin_amdgcn_global_load_lds((as1p)g, (as3p)lds, 16, 0, 0);
}

DEV f32x4 mfma16(bf16x8 a, bf16x8 b, f32x4 c){
  return __builtin_amdgcn_mfma_f32_16x16x32_bf16(a, b, c, 0, 0, 0);
}
DEV f32x16 mfma32(bf16x8 a, bf16x8 b, f32x16 c){
  return __builtin_amdgcn_mfma_f32_32x32x16_bf16(a, b, c, 0, 0, 0);
}

DEV bf16x8 ld8(const u16* p){ return *(const bf16x8*)p; }

DEV float vexp2(float x){            // native 2^x
  float y; asm("v_exp_f32 %0, %1" : "=v"(y) : "v"(x)); return y;
}

DEV u32 cvtpk(float lo, float hi){
  u32 r; asm("v_cvt_pk_bf16_f32 %0, %1, %2" : "=v"(r) : "v"(lo), "v"(hi)); return r;
}
DEV void perm32swap(u32 &a, u32 &b){
  asm("v_permlane32_swap_b32 %0, %1" : "+v"(a), "+v"(b));
}
DEV bf16x8 frag4(u32 w0,u32 w1,u32 w2,u32 w3){
  union{ u32 w[4]; bf16x8 f; } u; u.w[0]=w0; u.w[1]=w1; u.w[2]=w2; u.w[3]=w3; return u.f;
}

// XOR swizzles (T2/T21)
DEV int swz64(int row, int blk){ return row*64 + ((blk ^ (row & 7)) << 3); } // 128B rows
DEV int swz32(int row, int blk){ return row*32 + ((blk ^ (row & 3)) << 3); } // 64B rows

// ---------------- fused cast f32 -> bf16 (x and enc in one launch) ----------------
__global__ __launch_bounds__(256) void castk2(const float* __restrict__ in0,
                                              u16* __restrict__ out0,
                                              const float* __restrict__ in1,
                                              u16* __restrict__ out1){
  const float* in = blockIdx.y ? in1 : in0;
  u16*        out = blockIdx.y ? out1 : out0;
  int i = blockIdx.x*256 + threadIdx.x;
  f32x4 v = *(const f32x4*)(in + (size_t)i*4);
  u16x4 o;
  #pragma unroll
  for(int j=0;j<4;j++) o[j] = cvt_bf16(v[j]);
  *(u16x4*)(out + (size_t)i*4) = o;
}

// -------- fused small pre-pass: bias concats (Q-bias pre-scaled) + mask bias --------
__global__ __launch_bounds__(256) void smallfuse(
    const float* __restrict__ sabq, const float* __restrict__ sabk,
    const float* __restrict__ sabv, const float* __restrict__ cabk,
    const float* __restrict__ cabv, const float* __restrict__ cabq,
    const int* __restrict__ pm,
    float* __restrict__ bqkv, float* __restrict__ bkvc,
    float* __restrict__ biasg, float* __restrict__ bqc){
  int i = blockIdx.x*256 + threadIdx.x;   // 0..8191
  if(i < 1024)       bqkv[i] = sabq[i]*SC;
  else if(i < 2048)  bqkv[i] = sabk[i-1024];
  else if(i < 3072)  bqkv[i] = sabv[i-2048];
  else if(i < 4096)  bkvc[i-3072] = cabk[i-3072];
  else if(i < 5120)  bkvc[i-3072] = cabv[i-4096];
  else if(i < 7168)  biasg[i-5120] = pm[i-5120] ? 0.f : -1e9f;
  else if(i < 8192)  bqc[i-7168] = cabq[i-7168]*SC;
}

// ---------------- weight transpose-cast: f32[K,N] -> bf16[N,K] (optional scale) -----
DEV void wcast_body(const float* __restrict__ W, u16* __restrict__ Wt,
                    int K, int N, int bx, int by, int tid, float scale){
  __shared__ u16 tile[64][66];
  const int k0 = bx*64, n0 = by*64;
  const int lr = tid >> 4, c4 = (tid & 15)*4;
  #pragma unroll
  for(int p=0;p<4;p++){
    const int r = lr + p*16;
    f32x4 v = *(const f32x4*)&W[(size_t)(k0+r)*N + n0 + c4];
    #pragma unroll
    for(int j=0;j<4;j++) tile[r][c4+j] = cvt_bf16(v[j]*scale);
  }
  __syncthreads();
  #pragma unroll
  for(int p=0;p<4;p++){
    const int n = lr + p*16;
    u16x4 u;
    #pragma unroll
    for(int j=0;j<4;j++) u[j] = tile[c4+j][n];
    *(u16x4*)&Wt[(size_t)(n0+n)*K + k0 + c4] = u;
  }
}

__global__ __launch_bounds__(256) void wcast_t(const float* __restrict__ W,
                                               u16* __restrict__ Wt, int K, int N){
  wcast_body(W, Wt, K, N, blockIdx.x, blockIdx.y, threadIdx.x, 1.f);
}

// eight 1024x1024 weights in one launch; slots 0 (Wq) and 4 (cWq) pre-scaled by SC
__global__ __launch_bounds__(256) void wcast8(
    const float* s0, const float* s1, const float* s2, const float* s3,
    const float* s4, const float* s5, const float* s6, const float* s7,
    u16* d0, u16* d1, u16* d2, u16* d3, u16* d4, u16* d5, u16* d6, u16* d7){
  const float* W; u16* Wt;
  switch(blockIdx.z){
    case 0: W=s0; Wt=d0; break;  case 1: W=s1; Wt=d1; break;
    case 2: W=s2; Wt=d2; break;  case 3: W=s3; Wt=d3; break;
    case 4: W=s4; Wt=d4; break;  case 5: W=s5; Wt=d5; break;
    case 6: W=s6; Wt=d6; break;  default: W=s7; Wt=d7; break;
  }
  const float scale = (blockIdx.z==0 || blockIdx.z==4) ? SC : 1.f;
  wcast_body(W, Wt, 1024, 1024, blockIdx.x, blockIdx.y, threadIdx.x, scale);
}

// ---------------- V transpose per (b,h): [B*L, ld] -> [B,H,64,L] ----------------
__global__ __launch_bounds__(256) void vtrans(const u16* __restrict__ V,
                                              u16* __restrict__ Vt, int L, int ld){
  __shared__ u16 tile[64][66];
  const int t0 = blockIdx.x*64;
  const int h = blockIdx.y, b = blockIdx.z;
  const int lr = threadIdx.x >> 4, c4 = (threadIdx.x & 15)*4;
  #pragma unroll
  for(int p=0;p<4;p++){
    const int r = lr + p*16;
    u16x4 v = *(const u16x4*)&V[(size_t)(b*L + t0 + r)*ld + h*64 + c4];
    #pragma unroll
    for(int j=0;j<4;j++) tile[r][c4+j] = v[j];
  }
  __syncthreads();
  #pragma unroll
  for(int p=0;p<4;p++){
    const int d = lr + p*16;
    u16x4 u;
    #pragma unroll
    for(int j=0;j<4;j++) u[j] = tile[c4+j][d];
    *(u16x4*)&Vt[((size_t)((b*16 + h)*64 + d))*L + t0 + c4] = u;
  }
}

// ---------------- GEMM: C[M,N] = A[M,K](bf16) * Bt[N,K](bf16)^T + bias ----------------
// R12-proven structure: double-buffered LDS, prefetch-1, one __syncthreads per K-step.
// (R13's counted-vmcnt triple-buffer was neutral-to-negative -- m131-m141 confirmed.)
template<int OMODE, int BN, int SPLITK>
__global__ __launch_bounds__(256, BN==128 ? 3 : 4) void gemm_bt(
    const u16* __restrict__ A, const u16* __restrict__ Bt,
    const float* __restrict__ bias, void* __restrict__ Cout0, void* __restrict__ Cout1,
    int N, int K)
{
  __shared__ __align__(16) u16 As[2][128*32];
  __shared__ __align__(16) u16 Bs[2][BN*32];
  constexpr int NJ = BN/32;
  const int tid = threadIdx.x, wave = tid>>6, lane = tid&63;
  const int fr = lane&15, fg = lane>>4;
  const int bm = blockIdx.x*128, bn = blockIdx.y*BN;
  const int part = (SPLITK>1) ? blockIdx.z : 0;
  const int Kp = K / SPLITK;
  const int kbase = part * Kp;
  const int wm = (wave>>1)*64, wn = (wave&1)*(BN/2);
  const f32x4 z4 = {0.f,0.f,0.f,0.f};
  f32x4 acc[4][NJ];
  #pragma unroll
  for(int i=0;i<4;i++)
    #pragma unroll
    for(int j=0;j<NJ;j++) acc[i][j] = z4;

  const int srA = wave*32 + (lane>>2);
  const int cl_l = (lane&3)*8;
  const int cl_g = ((lane&3) ^ ((lane>>2)&3))*8;
  const int srB = (BN==128) ? srA : (wave*16 + (lane>>2));
  const u16* gA = A  + (size_t)(bm + srA)*K + kbase + cl_g;
  const u16* gB = Bt + (size_t)(bn + srB)*K + kbase + cl_g;

  auto stage = [&](int p, int ko){
    u16* lA = &As[p][srA*32 + cl_l];
    u16* lB = &Bs[p][srB*32 + cl_l];
    gld16(lA,     gA + ko);
    gld16(lA+512, gA + ko + (size_t)16*K);
    gld16(lB,     gB + ko);
    if(BN==128) gld16(lB+512, gB + ko + (size_t)16*K);
  };

  const int nk = Kp >> 5;
  stage(0, 0);
  __syncthreads();
  for(int kt=0; kt<nk; ++kt){
    const int cur = kt & 1;
    if(kt+1 < nk) stage(cur^1, (kt+1)*32);
    bf16x8 af[4], bfv[NJ];
    #pragma unroll
    for(int i=0;i<4;i++) af[i] = ld8(&As[cur][swz32(wm + i*16 + fr, fg)]);
    #pragma unroll
    for(int j=0;j<NJ;j++) bfv[j] = ld8(&Bs[cur][swz32(wn + j*16 + fr, fg)]);
    __builtin_amdgcn_s_setprio(1);
    #pragma unroll
    for(int i=0;i<4;i++)
      #pragma unroll
      for(int j=0;j<NJ;j++)
        acc[i][j] = mfma16(af[i], bfv[j], acc[i][j]);
    __builtin_amdgcn_s_setprio(0);
    __syncthreads();
  }

  void* Cout = (part==0) ? Cout0 : Cout1;
  const int r0 = bm + wm + fg*4;
  const int c0 = bn + wn + fr;
  #pragma unroll
  for(int j=0;j<NJ;j++){
    const int col = c0 + j*16;
    const float bv = (part==0) ? bias[col] : 0.f;
    #pragma unroll
    for(int i=0;i<4;i++){
      #pragma unroll
      for(int r=0;r<4;r++){
        const float v = acc[i][j][r] + bv;
        const size_t idx = (size_t)(r0 + i*16 + r)*N + col;
        if(OMODE==0)      ((float*)Cout)[idx] = v;
        else if(OMODE==1) ((u16*)Cout)[idx]   = cvt_bf16(v);
        else              ((u16*)Cout)[idx]   = cvt_bf16(fmaxf(v, 0.f));
      }
    }
  }
}

// ---------------- flash attention, KV-split xNPART, FIXED-SHIFT softmax ------------
// Q pre-scaled by SC so scores are in exp2 units; P = 2^s directly (no online max:
// exact vs softmax modulo over/underflow, >100 exp2-units of margin).
// R9's proven schedule: double-buffered LDS (32 KiB), one __syncthreads per tile.
// Partials stored BF16. (256,4): VGPR ~60 fits -- (256,5) forced 48 and SPILLED (R7).
template<bool CAUSAL, int NPART>
__global__ __launch_bounds__(256,4) void attn3(
    const u16* __restrict__ Qg, int ldq, const u16* __restrict__ Kg, int ldk,
    const u16* __restrict__ Vt, const float* __restrict__ biasg,
    u16* __restrict__ O0, u16* __restrict__ O1,
    u16* __restrict__ O2, u16* __restrict__ O3,
    float* __restrict__ Ll, int Lk)
{
  __shared__ __align__(16) u16 Ks[2][64*64];
  __shared__ __align__(16) u16 Vs[2][64*64];
  constexpr int P2 = NPART*16;
  const int tid = threadIdx.x, wave = tid>>6, lane = tid&63;
  const int l31 = lane&31, hi = lane>>5;
  const int bid = blockIdx.x;
  const int g    = (bid&7)*4 + ((bid>>3)/P2);   // (b,h) group 0..31, XCD-resident
  const int rp   = (bid>>3)%P2;
  const int part = rp&(NPART-1), qb = rp/NPART;
  const int h = g&15, b = g>>4;
  // causal: pair-swizzle so heavy and light q-blocks interleave
  const int qi = CAUSAL ? ((qb&1) ? (15-(qb>>1)) : (qb>>1)) : qb;
  const int q0 = qi*128;
  const int qw = q0 + wave*32;
  const int qrow = qw + l31;                 // this lane's q-row (softmax owner)

  bf16x8 qf[4];
  {
    const u16* Qp = Qg + (size_t)(b*2048 + qrow)*ldq + h*64;
    #pragma unroll
    for(int c=0;c<4;c++) qf[c] = ld8(Qp + c*16 + hi*8);
  }

  f32x16 o0, o1;
  #pragma unroll
  for(int r=0;r<16;r++){ o0[r]=0.f; o1[r]=0.f; }
  float lsum = 0.f;

  const int srow = wave*16 + (lane>>3);
  const int cl_l = (lane&7)*8;
  const int cl_g = ((lane&7) ^ ((lane>>3)&7))*8;
  const u16* Kp = Kg + (size_t)(b*2048 + srow)*ldk + h*64 + cl_g;
  const u16* Vp = Vt + ((size_t)((b*16 + h)*64 + srow))*Lk + cl_g;

  auto stage = [&](int p, int kv0){
    u16* lK = &Ks[p][srow*64 + cl_l];
    u16* lV = &Vs[p][srow*64 + cl_l];
    gld16(lK,     Kp + (size_t)kv0*ldk);
    gld16(lK+512, Kp + (size_t)(kv0+8)*ldk);
    gld16(lV,     Vp + kv0);
    gld16(lV+512, Vp + kv0 + 8*(size_t)Lk);
  };

  // tile range for this part (variable split; empty parts write O=0, l=0)
  const int T  = CAUSAL ? (2*qi+2) : (Lk>>6);
  const int t0 = part*T/NPART, t1 = (part+1)*T/NPART;

  stage(0, t0*64);
  __syncthreads();
  for(int kt=t0; kt<t1; ++kt){
    const int cur = (kt-t0)&1;
    const int kv0 = kt*64;
    if(kt+1 < t1) stage(cur^1, (kt+1)*64);

    if(!CAUSAL || kv0 <= qw+31){   // wave-uniform: skip fully-masked tiles
      // S^T = K Q^T : lane holds col q=l31; rows k=(r&3)+8(r>>2)+4hi (+32 for s1)
      f32x16 s0, s1;
      #pragma unroll
      for(int r=0;r<16;r++){ s0[r]=0.f; s1[r]=0.f; }
      __builtin_amdgcn_s_setprio(1);
      #pragma unroll
      for(int c=0;c<4;c++){
        bf16x8 k0 = ld8(&Ks[cur][swz64(l31,      2*c+hi)]);
        bf16x8 k1 = ld8(&Ks[cur][swz64(32 + l31, 2*c+hi)]);
        s0 = mfma32(k0, qf[c], s0);
        s1 = mfma32(k1, qf[c], s1);
      }
      __builtin_amdgcn_s_setprio(0);

      float p[32];
      #pragma unroll
      for(int r=0;r<16;r++){ p[r]=s0[r]; p[16+r]=s1[r]; }

      if(CAUSAL){
        if(kv0 + 63 > qw){         // diagonal tile only
          #pragma unroll
          for(int n=0;n<2;n++)
            #pragma unroll
            for(int r=0;r<16;r++){
              const int kc = kv0 + 32*n + (r&3) + 8*(r>>2) + 4*hi;
              if(kc > qrow) p[16*n+r] = -1e9f;
            }
        }
      } else {
        #pragma unroll
        for(int n=0;n<2;n++)
          #pragma unroll
          for(int cq=0;cq<4;cq++){
            f32x4 bv = *(const f32x4*)&biasg[kv0 + 32*n + 8*cq + 4*hi];
            #pragma unroll
            for(int i=0;i<4;i++) p[16*n+4*cq+i] += bv[i];
          }
      }

      // fixed-shift softmax: P = 2^s, no max reduction, no rescale, no branches
      float rs0=0.f, rs1=0.f, rs2=0.f, rs3=0.f;
      #pragma unroll
      for(int r=0;r<8;r++){
        p[r]    = vexp2(p[r]);    rs0 += p[r];
        p[8+r]  = vexp2(p[8+r]);  rs1 += p[8+r];
        p[16+r] = vexp2(p[16+r]); rs2 += p[16+r];
        p[24+r] = vexp2(p[24+r]); rs3 += p[24+r];
      }
      float rs = (rs0+rs1) + (rs2+rs3);
      rs += __shfl_xor(rs, 32);
      lsum += rs;

      // P -> bf16 A-frags fully in-register (cvt_pk + permlane32_swap)
      u32 pw[16];
      #pragma unroll
      for(int n=0;n<2;n++)
        #pragma unroll
        for(int cp=0;cp<2;cp++){
          const int base = 16*n + 8*cp, cc = 2*n + cp;
          u32 a1 = cvtpk(p[base+0], p[base+1]);
          u32 a2 = cvtpk(p[base+2], p[base+3]);
          u32 b1 = cvtpk(p[base+4], p[base+5]);
          u32 b2 = cvtpk(p[base+6], p[base+7]);
          perm32swap(a1, b1);
          perm32swap(a2, b2);
          pw[4*cc+0]=a1; pw[4*cc+1]=a2; pw[4*cc+2]=b1; pw[4*cc+3]=b2;
        }

      // O += P V
      __builtin_amdgcn_s_setprio(1);
      #pragma unroll
      for(int cc=0;cc<4;cc++){
        bf16x8 pf = frag4(pw[4*cc], pw[4*cc+1], pw[4*cc+2], pw[4*cc+3]);
        bf16x8 v0 = ld8(&Vs[cur][swz64(l31,      2*cc+hi)]);
        bf16x8 v1 = ld8(&Vs[cur][swz64(32 + l31, 2*cc+hi)]);
        o0 = mfma32(pf, v0, o0);
        o1 = mfma32(pf, v1, o1);
      }
      __builtin_amdgcn_s_setprio(0);
    }
    __syncthreads();   // drains prefetch (overlapped) + protects restage
  }

  // epilogue: unnormalized O partial (bf16) + per-row l, [part][h][row] layout
  u16* Obase = (part==0) ? O0 : (part==1) ? O1 : (part==2) ? O2 : O3;
  u16* Op = Obase + (size_t)(b*2048 + qw)*1024 + h*64;
  #pragma unroll
  for(int r=0;r<16;r++){
    const int qidx = (r&3) + 8*(r>>2) + 4*hi;
    Op[(size_t)qidx*1024 + l31]      = cvt_bf16(o0[r]);
    Op[(size_t)qidx*1024 + 32 + l31] = cvt_bf16(o1[r]);
  }
  if(hi==0){
    const int mi = part*65536 + h*4096 + (b*2048 + qw + l31);
    Ll[mi] = lsum;
  }
}

// ---------------- attention partial combine over NP parts (fixed-shift: sum/sum) ----
template<int NP>
__global__ __launch_bounds__(256) void att_combine(
    const u16* __restrict__ O0, const u16* __restrict__ O1,
    const u16* __restrict__ O2, const u16* __restrict__ O3,
    const float* __restrict__ Ll, u16* __restrict__ Ob)
{
  const int row = blockIdx.x, tid = threadIdx.x;
  const int h = tid>>4;
  const int mi = h*4096 + row;
  float denom = 0.f;
  #pragma unroll
  for(int p=0;p<NP;p++) denom += Ll[p*65536 + mi];
  const float inv = 1.f/denom;
  const size_t base = (size_t)row*1024 + tid*4;
  f32x4 acc = {0.f,0.f,0.f,0.f};
  #pragma unroll
  for(int p=0;p<NP;p++){
    const u16* Op = (p==0) ? O0 : (p==1) ? O1 : (p==2) ? O2 : O3;
    u16x4 a = *(const u16x4*)(Op + base);
    #pragma unroll
    for(int j=0;j<4;j++) acc[j] += bf2f(a[j]);
  }
  u16x4 o;
  #pragma unroll
  for(int j=0;j<4;j++) o[j] = cvt_bf16(acc[j]*inv);
  *(u16x4*)(Ob + base) = o;
}

// ------ fused add + layernorm, 3-input (f32 residual + two BF16 GEMM partials) ------
__global__ __launch_bounds__(256) void add_ln3(const float* __restrict__ X,
                        const u16* __restrict__ D1, const u16* __restrict__ D2,
                        const float* __restrict__ gam, const float* __restrict__ bet,
                        float* __restrict__ outf, u16* __restrict__ outb){
  __shared__ float red[8];
  const int tid = threadIdx.x, wave = tid>>6, lane = tid&63;
  const size_t base = ((size_t)blockIdx.x << 10) + tid*4;
  f32x4 xv = *(const f32x4*)(X + base);
  u16x4 d1 = *(const u16x4*)(D1 + base);
  u16x4 d2 = *(const u16x4*)(D2 + base);
  f32x4 v;
  #pragma unroll
  for(int j=0;j<4;j++) v[j] = xv[j] + bf2f(d1[j]) + bf2f(d2[j]);
  float s = v[0]+v[1]+v[2]+v[3];
  float q = v[0]*v[0]+v[1]*v[1]+v[2]*v[2]+v[3]*v[3];
  #pragma unroll
  for(int off=1;off<64;off<<=1){ s += __shfl_xor(s,off); q += __shfl_xor(q,off); }
  if(lane==0){ red[wave]=s; red[4+wave]=q; }
  __syncthreads();
  s = red[0]+red[1]+red[2]+red[3];
  q = red[4]+red[5]+red[6]+red[7];
  const float mean = s*(1.f/1024.f);
  const float var  = q*(1.f/1024.f) - mean*mean;
  const float rr = rsqrtf(var + 1e-5f);
  const int c = tid*4;
  f32x4 y;
  #pragma unroll
  for(int j=0;j<4;j++) y[j] = (v[j]-mean)*rr*gam[c+j] + bet[c+j];
  *(f32x4*)(outf + base) = y;
  if(outb){
    u16x4 ob;
    #pragma unroll
    for(int j=0;j<4;j++) ob[j] = cvt_bf16(y[j]);
    *(u16x4*)(outb + base) = ob;
  }
}

// ---------------- host orchestration ----------------
extern "C" void kernel_launch(void* const* d_in, const int* in_sizes, int n_in,
                              void* d_out, int out_size, void* d_ws, size_t ws_size,
                              hipStream_t stream)
{
  (void)in_sizes; (void)n_in; (void)out_size; (void)ws_size;
  const float* x    = (const float*)d_in[0];
  const float* enc  = (const float*)d_in[1];
  const int*   pmask= (const int*)d_in[3];
  const float* saWq = (const float*)d_in[4];  const float* sabq = (const float*)d_in[5];
  const float* saWk = (const float*)d_in[6];  const float* sabk = (const float*)d_in[7];
  const float* saWv = (const float*)d_in[8];  const float* sabv = (const float*)d_in[9];
  const float* saWo = (const float*)d_in[10]; const float* sabo = (const float*)d_in[11];
  const float* caWq = (const float*)d_in[12]; const float* cabq = (const float*)d_in[13];
  const float* caWk = (const float*)d_in[14]; const float* cabk = (const float*)d_in[15];
  const float* caWv = (const float*)d_in[16]; const float* cabv = (const float*)d_in[17];
  const float* caWo = (const float*)d_in[18]; const float* cabo = (const float*)d_in[19];
  const float* fW1  = (const float*)d_in[20]; const float* fb1  = (const float*)d_in[21];
  const float* fW2  = (const float*)d_in[22]; const float* fb2  = (const float*)d_in[23];
  const float* l1g  = (const float*)d_in[24]; const float* l1b  = (const float*)d_in[25];
  const float* l2g  = (const float*)d_in[26]; const float* l2b  = (const float*)d_in[27];
  const float* l3g  = (const float*)d_in[28]; const float* l3b  = (const float*)d_in[29];

  // workspace layout (~176 MB)
  char* wsp = (char*)d_ws;
  size_t off = 0;
  auto take = [&](size_t bytes)->void*{ void* p = wsp + off; off += (bytes + 255) & ~(size_t)255; return p; };
  u16* slotA  = (u16*)take(8388608);    // Xbf -> Qcb -> an2b
  u16* Encb   = (u16*)take(8388608);
  u16* WqkvT  = (u16*)take(6291456);    // [3072][1024]
  u16* cWqT   = (u16*)take(2097152);
  u16* cWkvT  = (u16*)take(4194304);    // [2048][1024]
  u16* WoT    = (u16*)take(2097152);
  u16* cWoT   = (u16*)take(2097152);
  u16* W1T    = (u16*)take(8388608);
  u16* W2T    = (u16*)take(8388608);
  float* bqkv = (float*)take(16384);    // [3072]
  float* bkvc = (float*)take(16384);    // [2048]
  float* biasg= (float*)take(16384);    // padding-mask additive bias [2048]
  float* bqc  = (float*)take(16384);    // scaled cross Q bias [1024]
  u16* slotB  = (u16*)take(25165824);   // QKVb [4096][3072] -> KVc [4096][2048]
  u16* Vtb    = (u16*)take(8388608);
  u16* Ob     = (u16*)take(8388608);
  u16* an1b   = (u16*)take(8388608);    // bf16 addnorm1; head doubles as attn l scratch
  float* projf= (float*)take(16777216); // bf16 partial pair (2x8MB) per phase
  float* an1f = (float*)take(16777216); // addnorm1 f32; self attn partials; FF2 part 1
  float* an2f = (float*)take(16777216); // addnorm2 f32; Wo partial 1
  char* ffhb  = (char*)take(33554432);  // FF hidden; cross attn partials; cWo part 1
  u16* Xbf = slotA;  u16* Qcb = slotA;  u16* an2b = slotA;
  u16* QKVb = slotB; u16* KVc = slotB;
  u16* ffh   = (u16*)ffhb;
  // Self-attn bf16 partials (8 MB each): parts 0,1 in projf; parts 2,3 in an1f.
  u16* S0 = (u16*)projf;  u16* S1 = S0 + 4194304;
  u16* S2 = (u16*)an1f;   u16* S3 = S2 + 4194304;
  // Cross-attn bf16 partials: parts 0,1 in ffhb (an1f live during cross).
  u16* C0 = (u16*)ffhb;   u16* C1 = C0 + 4194304;
  // Split-K GEMM bf16 partial pairs (8 MB each):
  u16* P0 = (u16*)projf;              // part 0 (all three split GEMMs)
  u16* PWo = (u16*)an2f;              // Wo  part 1 (an2f dead pre-ln1)
  u16* PcWo= (u16*)ffhb;              // cWo part 1 (ffhb dead post-combine)
  u16* PFF = (u16*)an1f;              // FF2 part 1 (an1f dead post-ln2)
  float* Llb = (float*)an1b;            // [4][65536] = 1 MB (an1b dead during attn)

  // pre-pass (5 dispatches)
  castk2<<<dim3(4096,2),256,0,stream>>>(x, Xbf, enc, Encb);
  wcast8<<<dim3(16,16,8),256,0,stream>>>(
      saWq, saWk, saWv, saWo, caWq, caWk, caWv, caWo,
      WqkvT, WqkvT + 1024*1024, WqkvT + 2*1024*1024, WoT,
      cWqT, cWkvT, cWkvT + 1024*1024, cWoT);
  wcast_t<<<dim3(16,64),256,0,stream>>>(fW1, W1T, 1024, 4096);
  wcast_t<<<dim3(64,16),256,0,stream>>>(fW2, W2T, 4096, 1024);
  smallfuse<<<32,256,0,stream>>>(sabq, sabk, sabv, cabk, cabv, cabq, pmask,
                                 bqkv, bkvc, biasg, bqc);

  // self-attention (causal KV-split x4: critical path 8 tiles)
  gemm_bt<1,128,1><<<dim3(32,24),256,0,stream>>>(Xbf, WqkvT, bqkv, QKVb, nullptr, 3072, 1024);
  vtrans<<<dim3(32,16,2),256,0,stream>>>(QKVb + 2048, Vtb, 2048, 3072);
  attn3<true,4><<<2048,256,0,stream>>>(QKVb, 3072, QKVb + 1024, 3072, Vtb, nullptr,
                                       S0, S1, S2, S3, Llb, 2048);
  att_combine<4><<<4096,256,0,stream>>>(S0, S1, S2, S3, Llb, Ob);
  gemm_bt<1,128,2><<<dim3(32,8,2),256,0,stream>>>(Ob, WoT, sabo, P0, PWo, 1024, 1024);
  add_ln3<<<4096,256,0,stream>>>(x, P0, PWo, l1g, l1b, an1f, an1b);

  // cross-attention (KV-split x2; an1f LIVE -> partials in ffhb)
  gemm_bt<1,64,1><<<dim3(32,16),256,0,stream>>>(an1b, cWqT, bqc, Qcb, nullptr, 1024, 1024);
  gemm_bt<1,128,1><<<dim3(32,16),256,0,stream>>>(Encb, cWkvT, bkvc, KVc, nullptr, 2048, 1024);
  vtrans<<<dim3(32,16,2),256,0,stream>>>(KVc + 1024, Vtb, 2048, 2048);
  attn3<false,2><<<1024,256,0,stream>>>(Qcb, 1024, KVc, 2048, Vtb, biasg,
                                        C0, C1, nullptr, nullptr, Llb, 2048);
  att_combine<2><<<4096,256,0,stream>>>(C0, C1, nullptr, nullptr, Llb, Ob);
  gemm_bt<1,128,2><<<dim3(32,8,2),256,0,stream>>>(Ob, cWoT, cabo, P0, PcWo, 1024, 1024);
  add_ln3<<<4096,256,0,stream>>>(an1f, P0, PcWo, l2g, l2b, an2f, an2b);

  // feed-forward (FF2 split-K: bf16 partials in P0 + PFF, summed by add_ln3)
  gemm_bt<2,128,1><<<dim3(32,32),256,0,stream>>>(an2b, W1T, fb1, ffh, nullptr, 4096, 1024);
  gemm_bt<1,128,2><<<dim3(32,8,2),256,0,stream>>>(ffh, W2T, fb2, P0, PFF, 1024, 4096);
  add_ln3<<<4096,256,0,stream>>>(an2f, P0, PFF, l3g, l3b, (float*)d_out, nullptr);
}